// Round 5
// baseline (3537.356 us; speedup 1.0000x reference)
//
#include <hip/hip_runtime.h>
#include <hip/hip_fp16.h>
#include <math.h>

static constexpr int HS = 64;
static constexpr int HV = 32;
static constexpr int NB = 32;
static constexpr float CUTR = 5.0f;
static constexpr float SQRT3 = 1.7320508075688772f;
static constexpr float C2C = 2.7386127875258306f; // sqrt(7.5)

// feature record per node: 192 halves (384B, 3 cache lines)
// [0..63] sp ; [64+32*d+h] vp plane d
static constexpr int FSTR = 192;

union HU { unsigned u; __half2 h; };

__device__ inline unsigned pack2(float a, float b) {
    HU x;
    x.h = __halves2half2(__float2half_rn(a), __float2half_rn(b));
    return x.u;
}
__device__ inline float2 unpack2(unsigned u) {
    HU x; x.u = u;
    return __half22float2(x.h);
}

// ---------------- CSR build ----------------

__global__ void count_kernel(const int* __restrict__ ei, int* __restrict__ counts, int E) {
    int e = blockIdx.x * blockDim.x + threadIdx.x;
    if (e < E) atomicAdd(&counts[ei[E + e]], 1);
}

__global__ __launch_bounds__(1024) void scan_kernel(const int* __restrict__ counts,
                                                    int* __restrict__ row_ptr,
                                                    int* __restrict__ cursor, int N) {
    __shared__ int part[1024];
    int t = threadIdx.x;
    int chunk = (N + 1023) >> 10;
    int beg = t * chunk, end = min(beg + chunk, N);
    int s = 0;
    for (int i = beg; i < end; ++i) s += counts[i];
    part[t] = s;
    __syncthreads();
    for (int off = 1; off < 1024; off <<= 1) {
        int v = (t >= off) ? part[t - off] : 0;
        __syncthreads();
        part[t] += v;
        __syncthreads();
    }
    int base = (t == 0) ? 0 : part[t - 1];
    for (int i = beg; i < end; ++i) {
        row_ptr[i] = base;
        cursor[i] = base;
        base += counts[i];
    }
    if (t == 1023) row_ptr[N] = part[1023];
}

// Per-edge record, 16 dwords = 64B, dst-sorted:
// [0]=src  [1..3]=d0,d1,d2 (f32)
// [4+3l .. 6+3l] = layer-l coeffs as fp16 pairs: (a,b),(c2,q3),(q4,pad)
__global__ void build_kernel(const int* __restrict__ ei, const float* __restrict__ pos,
                             const float* __restrict__ shifts, const float* __restrict__ Wr,
                             const float* __restrict__ Wrb, int* __restrict__ cursor,
                             unsigned* __restrict__ recs, int E) {
    int e = blockIdx.x * blockDim.x + threadIdx.x;
    if (e >= E) return;
    int src = ei[e], dst = ei[E + e];
    float ev0 = pos[dst * 3 + 0] - pos[src * 3 + 0] + shifts[e * 3 + 0];
    float ev1 = pos[dst * 3 + 1] - pos[src * 3 + 1] + shifts[e * 3 + 1];
    float ev2 = pos[dst * 3 + 2] - pos[src * 3 + 2] + shifts[e * 3 + 2];
    float r = sqrtf(ev0 * ev0 + ev1 * ev1 + ev2 * ev2);
    float rinv = 1.0f / fmaxf(r, 1e-8f);
    float d0 = ev0 * rinv, d1 = ev1 * rinv, d2 = ev2 * rinv;
    float u = r * (1.0f / CUTR);
    float gate = 0.0f;
    if (u < 1.0f) {
        float inner = 1.0f - u * u;
        gate = __expf(1.0f - 1.0f / inner);
    }
    float wacc[15];
#pragma unroll
    for (int k = 0; k < 15; ++k) wacc[k] = 0.0f;
    const float inv_w = (float)NB / CUTR;
    for (int b = 0; b < NB; ++b) {
        float t = (r - (float)b * (CUTR / (NB - 1))) * inv_w;
        float rb = __expf(-0.5f * t * t);
#pragma unroll
        for (int k = 0; k < 15; ++k)
            wacc[k] += rb * Wr[(k / 5) * (NB * 5) + b * 5 + (k % 5)];
    }
    unsigned rec[16];
    rec[0] = (unsigned)src;
    rec[1] = __float_as_uint(d0);
    rec[2] = __float_as_uint(d1);
    rec[3] = __float_as_uint(d2);
#pragma unroll
    for (int l = 0; l < 3; ++l) {
        float w0 = gate * wacc[l * 5 + 0] + Wrb[l * 5 + 0];
        float w1 = gate * wacc[l * 5 + 1] + Wrb[l * 5 + 1];
        float w2 = gate * wacc[l * 5 + 2] + Wrb[l * 5 + 2];
        float w3 = gate * wacc[l * 5 + 3] + Wrb[l * 5 + 3];
        float w4 = gate * wacc[l * 5 + 4] + Wrb[l * 5 + 4];
        float a  = gate * w0;
        float b  = gate * w1 * SQRT3;
        float c2 = gate * w2 * SQRT3;
        float q4 = gate * w4 * C2C;
        float q3 = gate * w3 - q4 * (1.0f / 3.0f);
        rec[4 + 3 * l] = pack2(a, b);
        rec[5 + 3 * l] = pack2(c2, q3);
        rec[6 + 3 * l] = pack2(q4, 0.0f);
    }
    rec[13] = rec[14] = rec[15] = 0u;
    int p = atomicAdd(&cursor[dst], 1);
    uint4* o = (uint4*)(recs + (size_t)p * 16);
    const uint4* s4 = (const uint4*)rec;
#pragma unroll
    for (int k = 0; k < 4; ++k) o[k] = s4[k];
}

// ---------------- weight composition ----------------
__global__ void compose_kernel(const float* __restrict__ Ws, const float* __restrict__ Wv,
                               const float* __restrict__ Wos, const float* __restrict__ Wov,
                               float* __restrict__ Ms12, float* __restrict__ Mv12) {
    int t = blockIdx.x * blockDim.x + threadIdx.x;
    if (t < 2 * 4096) {
        int l = t >> 12;
        int idx = t & 4095;
        int j = idx >> 6, k = idx & 63;
        const float* A = Wos + l * 4096;
        const float* B = Ws + (l + 1) * 4096;
        float acc = 0.0f;
        for (int m = 0; m < 64; ++m) acc += A[j * 64 + m] * B[m * 64 + k];
        Ms12[t] = acc;
    } else if (t < 2 * 4096 + 2 * 1024) {
        int q = t - 2 * 4096;
        int l = q >> 10;
        int idx = q & 1023;
        int j = idx >> 5, k = idx & 31;
        const float* A = Wov + l * 1024;
        const float* B = Wv + (l + 1) * 1024;
        float acc = 0.0f;
        for (int m = 0; m < 32; ++m) acc += A[j * 32 + m] * B[m * 32 + k];
        Mv12[q] = acc;
    }
}

// ---------------- node transform ----------------
// MODE 0: raw features (s: N x 64 f32, v: N x 32 x 3 AoS f32) -> packed fp16 feat
// MODE 1: agg buffers (as: N x 64 f32, avT: 3 planes N x 32 f32) -> packed fp16 feat
// MODE 2: like 1 but writes interleaved final f32 output (N x 160)
template <int MODE>
__global__ void node_transform(const float* __restrict__ s_in, const float* __restrict__ v_in,
                               const float* __restrict__ Ms, const float* __restrict__ Mv,
                               __half* __restrict__ feat, float* __restrict__ out160, int N) {
    __shared__ float sMs[64 * 64];
    __shared__ float sMv[32 * 32];
    for (int i = threadIdx.x; i < 4096; i += blockDim.x) sMs[i] = Ms[i];
    for (int i = threadIdx.x; i < 1024; i += blockDim.x) sMv[i] = Mv[i];
    __syncthreads();
    int wid = threadIdx.x >> 6, lane = threadIdx.x & 63;
    int n = blockIdx.x * (blockDim.x >> 6) + wid;
    if (n >= N) return;
    float asv = s_in[(size_t)n * 64 + lane];
    int h = lane & 31;
    float av0, av1, av2;
    if (MODE == 0) {
        av0 = v_in[(size_t)n * 96 + h * 3 + 0];
        av1 = v_in[(size_t)n * 96 + h * 3 + 1];
        av2 = v_in[(size_t)n * 96 + h * 3 + 2];
    } else {
        av0 = v_in[(size_t)n * 32 + h];
        av1 = v_in[(size_t)N * 32 + (size_t)n * 32 + h];
        av2 = v_in[(size_t)2 * N * 32 + (size_t)n * 32 + h];
    }
    float acc = 0.0f;
    for (int i = 0; i < 64; ++i)
        acc += __shfl(asv, i) * sMs[i * 64 + lane];
    float vacc0 = 0.0f, vacc1 = 0.0f, vacc2 = 0.0f;
    for (int g = 0; g < 32; ++g) {
        float b0 = __shfl(av0, g), b1 = __shfl(av1, g), b2 = __shfl(av2, g);
        float m = sMv[g * 32 + h];
        vacc0 += b0 * m; vacc1 += b1 * m; vacc2 += b2 * m;
    }
    if (MODE == 2) {
        out160[(size_t)n * 160 + lane] = acc;
        if (lane < 32) {
            out160[(size_t)n * 160 + 64 + lane * 3 + 0] = vacc0;
            out160[(size_t)n * 160 + 64 + lane * 3 + 1] = vacc1;
            out160[(size_t)n * 160 + 64 + lane * 3 + 2] = vacc2;
        }
    } else {
        feat[(size_t)n * FSTR + lane] = __float2half(acc);
        if (lane < 32) {
            feat[(size_t)n * FSTR + 64 + lane] = __float2half(vacc0);
            feat[(size_t)n * FSTR + 96 + lane] = __float2half(vacc1);
            feat[(size_t)n * FSTR + 128 + lane] = __float2half(vacc2);
        }
    }
}

// ---------------- edge aggregation: persistent waves, work-stealing, 4-edge pipelined ----------------
__global__ __launch_bounds__(256, 4) void edge_agg(
        const unsigned* __restrict__ recs, const int* __restrict__ row_ptr,
        const __half* __restrict__ feat,
        const float* __restrict__ Uvs_l, const float* __restrict__ Usv_l,
        float* __restrict__ as_out, float* __restrict__ avT_out,
        int* __restrict__ ctr, int N, int E, int c0) {
    __shared__ float sUvs[32 * 64];
    __shared__ float sUsv[64 * 32];
    for (int i = threadIdx.x; i < 2048; i += blockDim.x) {
        sUvs[i] = Uvs_l[i];
        sUsv[i] = Usv_l[i];
    }
    __syncthreads();
    int lane = threadIdx.x & 63;
    bool lo = lane < 32;
    int h = lane & 31;

    for (;;) {
        int n = 0;
        if (lane == 0) n = atomicAdd(ctr, 1);
        n = __shfl(n, 0);
        if (n >= N) break;
        int beg = row_ptr[n], end = row_ptr[n + 1];

        float S0 = 0.f, T10 = 0.f, T11 = 0.f, T12 = 0.f;
        float A1 = 0.f, V0 = 0.f, V1 = 0.f, V2 = 0.f;

        int i = beg;
        // prologue rec load: lane l holds dword l of 4 consecutive recs
        unsigned regR = recs[(size_t)min(i, E) * 16 + lane];
        while (i < end) {
            int nxt = i + 4;
            // prefetch next 4 recs (stays in flight across the gathers)
            unsigned regN = recs[(size_t)min(nxt, E) * 16 + lane];

            // broadcast src indices, clamp (tail lanes carry garbage)
            int sv[4];
#pragma unroll
            for (int j = 0; j < 4; ++j) {
                unsigned s = (unsigned)__shfl((int)regR, 16 * j + 0);
                sv[j] = (int)min(s, (unsigned)(N - 1));
            }
            // issue all sp gathers
            __half spv[4];
#pragma unroll
            for (int j = 0; j < 4; ++j)
                spv[j] = feat[(size_t)sv[j] * FSTR + lane];
            // issue all vp gathers (lanes < 32)
            __half vv[4][3];
            if (lo) {
#pragma unroll
                for (int j = 0; j < 4; ++j) {
                    const __half* fb = feat + (size_t)sv[j] * FSTR + 64 + lane;
                    vv[j][0] = fb[0];
                    vv[j][1] = fb[32];
                    vv[j][2] = fb[64];
                }
            }
            // broadcast d and coeffs (VALU work overlapped with gather latency)
            float dv[4][3];
            unsigned cu[4][3];
#pragma unroll
            for (int j = 0; j < 4; ++j) {
                dv[j][0] = __uint_as_float(__shfl((int)regR, 16 * j + 1));
                dv[j][1] = __uint_as_float(__shfl((int)regR, 16 * j + 2));
                dv[j][2] = __uint_as_float(__shfl((int)regR, 16 * j + 3));
                bool valid = (i + j) < end;
                cu[j][0] = valid ? (unsigned)__shfl((int)regR, 16 * j + c0) : 0u;
                cu[j][1] = valid ? (unsigned)__shfl((int)regR, 16 * j + c0 + 1) : 0u;
                cu[j][2] = valid ? (unsigned)__shfl((int)regR, 16 * j + c0 + 2) : 0u;
            }
            // accumulate
#pragma unroll
            for (int j = 0; j < 4; ++j) {
                float2 f0 = unpack2(cu[j][0]); // a, b
                float2 f1 = unpack2(cu[j][1]); // c2, q3
                float2 f2 = unpack2(cu[j][2]); // q4, -
                float spc = __half2float(spv[j]);
                S0 += f0.x * spc;
                float c2 = f1.x;
                T10 += (c2 * dv[j][0]) * spc;
                T11 += (c2 * dv[j][1]) * spc;
                T12 += (c2 * dv[j][2]) * spc;
                if (lo) {
                    float v0 = __half2float(vv[j][0]);
                    float v1 = __half2float(vv[j][1]);
                    float v2 = __half2float(vv[j][2]);
                    float pdot = dv[j][0] * v0 + dv[j][1] * v1 + dv[j][2] * v2;
                    A1 += f0.y * pdot;
                    float qp = f2.x * pdot;
                    V0 += f1.y * v0 + qp * dv[j][0];
                    V1 += f1.y * v1 + qp * dv[j][1];
                    V2 += f1.y * v2 + qp * dv[j][2];
                }
            }
            regR = regN;
            i = nxt;
        }

        // agg_s[c] = S0 + sum_h A1[h] * Uvs[h,c]
        float aggs = S0;
        for (int h2 = 0; h2 < 32; ++h2)
            aggs += __shfl(A1, h2) * sUvs[h2 * 64 + lane];
        as_out[(size_t)n * 64 + lane] = aggs;
        // agg_v[h,d] = V[h,d] + sum_c T1[c,d] * Usv[c,h]
        float av0 = V0, av1 = V1, av2 = V2;
        for (int c = 0; c < 64; ++c) {
            float uu = sUsv[c * 32 + h];
            av0 += __shfl(T10, c) * uu;
            av1 += __shfl(T11, c) * uu;
            av2 += __shfl(T12, c) * uu;
        }
        if (lo) {
            avT_out[(size_t)n * 32 + lane] = av0;
            avT_out[(size_t)N * 32 + (size_t)n * 32 + lane] = av1;
            avT_out[(size_t)2 * N * 32 + (size_t)n * 32 + lane] = av2;
        }
    }
}

// ---------------- host ----------------

extern "C" void kernel_launch(void* const* d_in, const int* in_sizes, int n_in,
                              void* d_out, int out_size, void* d_ws, size_t ws_size,
                              hipStream_t stream) {
    const float* pos    = (const float*)d_in[0];
    const float* sfeat  = (const float*)d_in[1];
    const float* vfeat  = (const float*)d_in[2];
    const float* shifts = (const float*)d_in[3];
    const int*   ei     = (const int*)d_in[4];
    const float* Ws     = (const float*)d_in[5];
    const float* Wv     = (const float*)d_in[6];
    const float* Uvs    = (const float*)d_in[7];
    const float* Usv    = (const float*)d_in[8];
    const float* Wr     = (const float*)d_in[9];
    const float* Wrb    = (const float*)d_in[10];
    const float* Wos    = (const float*)d_in[11];
    const float* Wov    = (const float*)d_in[12];
    float* out = (float*)d_out;

    const int N = in_sizes[0] / 3;
    const int E = in_sizes[4] / 2;

    char* w = (char*)d_ws;
    auto alloc = [&](size_t bytes) {
        char* p = w;
        w += (bytes + 255) & ~(size_t)255;
        return p;
    };
    int* counts     = (int*)alloc((size_t)N * 4);
    int* row_ptr    = (int*)alloc((size_t)(N + 1) * 4);
    int* cursor     = (int*)alloc((size_t)N * 4);
    int* ctrs       = (int*)alloc(3 * 4);
    float* Ms12     = (float*)alloc(2 * 4096 * 4);
    float* Mv12     = (float*)alloc(2 * 1024 * 4);
    __half* feat    = (__half*)alloc((size_t)N * FSTR * 2);
    float* asB      = (float*)alloc((size_t)N * 64 * 4);
    float* avB      = (float*)alloc((size_t)N * 32 * 3 * 4);
    unsigned* recs  = (unsigned*)alloc((size_t)(E + 8) * 64);

    hipMemsetAsync(counts, 0, (size_t)N * 4, stream);
    hipMemsetAsync(ctrs, 0, 3 * 4, stream);

    int eb = (E + 255) / 256;
    count_kernel<<<eb, 256, 0, stream>>>(ei, counts, E);
    scan_kernel<<<1, 1024, 0, stream>>>(counts, row_ptr, cursor, N);
    build_kernel<<<eb, 256, 0, stream>>>(ei, pos, shifts, Wr, Wrb, cursor, recs, E);
    compose_kernel<<<40, 256, 0, stream>>>(Ws, Wv, Wos, Wov, Ms12, Mv12);

    int nb = (N + 3) / 4;
    int pb = 2048; // persistent blocks for edge_agg

    // layer 0
    node_transform<0><<<nb, 256, 0, stream>>>(sfeat, vfeat, Ws, Wv, feat, nullptr, N);
    edge_agg<<<pb, 256, 0, stream>>>(recs, row_ptr, feat, Uvs, Usv, asB, avB, ctrs + 0, N, E, 4);
    // layer 1
    node_transform<1><<<nb, 256, 0, stream>>>(asB, avB, Ms12, Mv12, feat, nullptr, N);
    edge_agg<<<pb, 256, 0, stream>>>(recs, row_ptr, feat, Uvs + 2048, Usv + 2048, asB, avB, ctrs + 1, N, E, 7);
    // layer 2
    node_transform<1><<<nb, 256, 0, stream>>>(asB, avB, Ms12 + 4096, Mv12 + 1024, feat, nullptr, N);
    edge_agg<<<pb, 256, 0, stream>>>(recs, row_ptr, feat, Uvs + 4096, Usv + 4096, asB, avB, ctrs + 2, N, E, 10);
    // final output transform
    node_transform<2><<<nb, 256, 0, stream>>>(asB, avB, Wos + 2 * 4096, Wov + 2 * 1024, nullptr, out, N);
}

// Round 7
// 2221.902 us; speedup vs baseline: 1.5920x; 1.5920x over previous
//
#include <hip/hip_runtime.h>
#include <hip/hip_fp16.h>
#include <math.h>

static constexpr int NB = 32;
static constexpr float CUTR = 5.0f;
static constexpr float SQRT3 = 1.7320508075688772f;
static constexpr float C2C = 2.7386127875258306f; // sqrt(7.5)

// feature record per node: 192 halves (384B, 6 cache lines, 5 touched/edge)
// halves [0..63] sp ; [64+2h,65+2h] = (v0,v1) ; [128+h] = v2 ; [160..191] pad
static constexpr int FSTR = 192;

union HU { unsigned u; __half2 h; };

__device__ inline unsigned pack2(float a, float b) {
    HU x;
    x.h = __halves2half2(__float2half_rn(a), __float2half_rn(b));
    return x.u;
}
__device__ inline float2 unpack2(unsigned u) {
    HU x; x.u = u;
    return __half22float2(x.h);
}

// ---------------- CSR build ----------------

__global__ void count_kernel(const int* __restrict__ ei, int* __restrict__ counts, int E) {
    int e = blockIdx.x * blockDim.x + threadIdx.x;
    if (e < E) atomicAdd(&counts[ei[E + e]], 1);
}

__global__ __launch_bounds__(1024) void scan_kernel(const int* __restrict__ counts,
                                                    int* __restrict__ row_ptr,
                                                    int* __restrict__ cursor, int N) {
    __shared__ int part[1024];
    int t = threadIdx.x;
    int chunk = (N + 1023) >> 10;
    int beg = t * chunk, end = min(beg + chunk, N);
    int s = 0;
    for (int i = beg; i < end; ++i) s += counts[i];
    part[t] = s;
    __syncthreads();
    for (int off = 1; off < 1024; off <<= 1) {
        int v = (t >= off) ? part[t - off] : 0;
        __syncthreads();
        part[t] += v;
        __syncthreads();
    }
    int base = (t == 0) ? 0 : part[t - 1];
    for (int i = beg; i < end; ++i) {
        row_ptr[i] = base;
        cursor[i] = base;
        base += counts[i];
    }
    if (t == 1023) row_ptr[N] = part[1023];
}

// recG[e] = (src, d0, d1, d2)   16B
// recC[l*Epad + e] = (pack(a,b), pack(c2,q3), pack(q4,0), 0)   16B per layer
__global__ void build_kernel(const int* __restrict__ ei, const float* __restrict__ pos,
                             const float* __restrict__ shifts, const float* __restrict__ Wr,
                             const float* __restrict__ Wrb, int* __restrict__ cursor,
                             uint4* __restrict__ recG, uint4* __restrict__ recC,
                             int E, int Epad) {
    int e = blockIdx.x * blockDim.x + threadIdx.x;
    if (e >= E) return;
    int src = ei[e], dst = ei[E + e];
    float ev0 = pos[dst * 3 + 0] - pos[src * 3 + 0] + shifts[e * 3 + 0];
    float ev1 = pos[dst * 3 + 1] - pos[src * 3 + 1] + shifts[e * 3 + 1];
    float ev2 = pos[dst * 3 + 2] - pos[src * 3 + 2] + shifts[e * 3 + 2];
    float r = sqrtf(ev0 * ev0 + ev1 * ev1 + ev2 * ev2);
    float rinv = 1.0f / fmaxf(r, 1e-8f);
    float d0 = ev0 * rinv, d1 = ev1 * rinv, d2 = ev2 * rinv;
    float u = r * (1.0f / CUTR);
    float gate = 0.0f;
    if (u < 1.0f) {
        float inner = 1.0f - u * u;
        gate = __expf(1.0f - 1.0f / inner);
    }
    float wacc[15];
#pragma unroll
    for (int k = 0; k < 15; ++k) wacc[k] = 0.0f;
    const float inv_w = (float)NB / CUTR;
    for (int b = 0; b < NB; ++b) {
        float t = (r - (float)b * (CUTR / (NB - 1))) * inv_w;
        float rb = __expf(-0.5f * t * t);
#pragma unroll
        for (int k = 0; k < 15; ++k)
            wacc[k] += rb * Wr[(k / 5) * (NB * 5) + b * 5 + (k % 5)];
    }
    int p = atomicAdd(&cursor[dst], 1);
    recG[p] = make_uint4((unsigned)src, __float_as_uint(d0), __float_as_uint(d1), __float_as_uint(d2));
#pragma unroll
    for (int l = 0; l < 3; ++l) {
        float w0 = gate * wacc[l * 5 + 0] + Wrb[l * 5 + 0];
        float w1 = gate * wacc[l * 5 + 1] + Wrb[l * 5 + 1];
        float w2 = gate * wacc[l * 5 + 2] + Wrb[l * 5 + 2];
        float w3 = gate * wacc[l * 5 + 3] + Wrb[l * 5 + 3];
        float w4 = gate * wacc[l * 5 + 4] + Wrb[l * 5 + 4];
        float a  = gate * w0;
        float b  = gate * w1 * SQRT3;
        float c2 = gate * w2 * SQRT3;
        float q4 = gate * w4 * C2C;
        float q3 = gate * w3 - q4 * (1.0f / 3.0f);
        recC[(size_t)l * Epad + p] = make_uint4(pack2(a, b), pack2(c2, q3), pack2(q4, 0.0f), 0u);
    }
}

// ---------------- weight composition ----------------
__global__ void compose_kernel(const float* __restrict__ Ws, const float* __restrict__ Wv,
                               const float* __restrict__ Wos, const float* __restrict__ Wov,
                               float* __restrict__ Ms12, float* __restrict__ Mv12) {
    int t = blockIdx.x * blockDim.x + threadIdx.x;
    if (t < 2 * 4096) {
        int l = t >> 12;
        int idx = t & 4095;
        int j = idx >> 6, k = idx & 63;
        const float* A = Wos + l * 4096;
        const float* B = Ws + (l + 1) * 4096;
        float acc = 0.0f;
        for (int m = 0; m < 64; ++m) acc += A[j * 64 + m] * B[m * 64 + k];
        Ms12[t] = acc;
    } else if (t < 2 * 4096 + 2 * 1024) {
        int q = t - 2 * 4096;
        int l = q >> 10;
        int idx = q & 1023;
        int j = idx >> 5, k = idx & 31;
        const float* A = Wov + l * 1024;
        const float* B = Wv + (l + 1) * 1024;
        float acc = 0.0f;
        for (int m = 0; m < 32; ++m) acc += A[j * 32 + m] * B[m * 32 + k];
        Mv12[q] = acc;
    }
}

// ---------------- node transform (LDS-staged, no shfl) ----------------
// MODE 0: raw features (s: N x 64 f32, v: N x 32 x 3 AoS f32) -> packed fp16 feat
// MODE 1: agg buffers (as: N x 64 f32, avT: 3 planes N x 32 f32) -> packed fp16 feat
// MODE 2: like 1 but writes interleaved final f32 output (N x 160)
template <int MODE>
__global__ void node_transform(const float* __restrict__ s_in, const float* __restrict__ v_in,
                               const float* __restrict__ Ms, const float* __restrict__ Mv,
                               __half* __restrict__ feat, float* __restrict__ out160, int N) {
    __shared__ float sMs[64 * 64];
    __shared__ float sMv[32 * 32];
    __shared__ float sS[4][64];
    __shared__ float sV[4][3][32];
    for (int i = threadIdx.x; i < 4096; i += blockDim.x) sMs[i] = Ms[i];
    for (int i = threadIdx.x; i < 1024; i += blockDim.x) sMv[i] = Mv[i];
    int wid = threadIdx.x >> 6, lane = threadIdx.x & 63;
    int n = blockIdx.x * 4 + wid;
    bool act = n < N;
    int h = lane & 31;
    float asv = 0.f, av0 = 0.f, av1 = 0.f, av2 = 0.f;
    if (act) {
        asv = s_in[(size_t)n * 64 + lane];
        if (MODE == 0) {
            av0 = v_in[(size_t)n * 96 + h * 3 + 0];
            av1 = v_in[(size_t)n * 96 + h * 3 + 1];
            av2 = v_in[(size_t)n * 96 + h * 3 + 2];
        } else {
            av0 = v_in[(size_t)n * 32 + h];
            av1 = v_in[(size_t)N * 32 + (size_t)n * 32 + h];
            av2 = v_in[(size_t)2 * N * 32 + (size_t)n * 32 + h];
        }
    }
    sS[wid][lane] = asv;
    if (lane < 32) {
        sV[wid][0][h] = av0;
        sV[wid][1][h] = av1;
        sV[wid][2][h] = av2;
    }
    __syncthreads();
    if (!act) return;
    float acc = 0.0f;
#pragma unroll 8
    for (int i = 0; i < 64; ++i)
        acc += sS[wid][i] * sMs[i * 64 + lane];
    float vacc0 = 0.0f, vacc1 = 0.0f, vacc2 = 0.0f;
#pragma unroll 8
    for (int g = 0; g < 32; ++g) {
        float m = sMv[g * 32 + h];
        vacc0 += sV[wid][0][g] * m;
        vacc1 += sV[wid][1][g] * m;
        vacc2 += sV[wid][2][g] * m;
    }
    if (MODE == 2) {
        out160[(size_t)n * 160 + lane] = acc;
        if (lane < 32) {
            out160[(size_t)n * 160 + 64 + h * 3 + 0] = vacc0;
            out160[(size_t)n * 160 + 64 + h * 3 + 1] = vacc1;
            out160[(size_t)n * 160 + 64 + h * 3 + 2] = vacc2;
        }
    } else {
        feat[(size_t)n * FSTR + lane] = __float2half(acc);
        if (lane < 32) {
            *((__half2*)(feat + (size_t)n * FSTR + 64) + h) =
                __halves2half2(__float2half(vacc0), __float2half(vacc1));
            feat[(size_t)n * FSTR + 128 + h] = __float2half(vacc2);
        }
    }
}

// ---------------- edge aggregation: scalar-path recs + 2-deep pipelined gathers ----------------
__global__ __launch_bounds__(256, 4) void edge_agg(
        const uint4* __restrict__ recG, const uint4* __restrict__ recC,
        const int* __restrict__ row_ptr, const __half* __restrict__ feat,
        const float* __restrict__ Uvs_l, const float* __restrict__ Usv_l,
        float* __restrict__ as_out, float* __restrict__ avT_out, int N) {
    __shared__ float sUvs[32 * 64];
    __shared__ float sUsv[64 * 32];
    for (int i = threadIdx.x; i < 2048; i += blockDim.x) {
        sUvs[i] = Uvs_l[i];
        sUsv[i] = Usv_l[i];
    }
    __syncthreads();
    int wid = threadIdx.x >> 6, lane = threadIdx.x & 63;
    int n = blockIdx.x * 4 + wid;
    if (n >= N) return;
    int beg = __builtin_amdgcn_readfirstlane(row_ptr[n]);
    int end = __builtin_amdgcn_readfirstlane(row_ptr[n + 1]);
    bool lo = lane < 32;
    int h = lane & 31;

    float S0 = 0.f, T10 = 0.f, T11 = 0.f, T12 = 0.f;
    float A1 = 0.f, V0 = 0.f, V1 = 0.f, V2 = 0.f;

#define DECLSET(S) \
    float S##d0[4], S##d1[4], S##d2[4]; \
    unsigned S##c0[4], S##c1[4], S##c2[4]; \
    __half S##sp[4]; __half2 S##v01[4]; __half S##v2[4];
    DECLSET(A)
    DECLSET(B)

#define LOADG(S, base) do { \
    int ib_ = __builtin_amdgcn_readfirstlane(base); \
    const uint4* Gp_ = recG + ib_; \
    const uint4* Cp_ = recC + ib_; \
    _Pragma("unroll") \
    for (int j_ = 0; j_ < 4; ++j_) { \
        uint4 g_ = Gp_[j_]; \
        uint4 c_ = Cp_[j_]; \
        bool val_ = (base + j_) < end; \
        S##d0[j_] = __uint_as_float(g_.y); \
        S##d1[j_] = __uint_as_float(g_.z); \
        S##d2[j_] = __uint_as_float(g_.w); \
        S##c0[j_] = val_ ? c_.x : 0u; \
        S##c1[j_] = val_ ? c_.y : 0u; \
        S##c2[j_] = val_ ? c_.z : 0u; \
        int sv_ = (int)min(g_.x, (unsigned)(N - 1)); \
        const __half* fb_ = feat + (size_t)sv_ * FSTR; \
        S##sp[j_] = fb_[lane]; \
        if (lo) { \
            S##v01[j_] = *(const __half2*)(fb_ + 64 + 2 * h); \
            S##v2[j_]  = fb_[128 + h]; \
        } \
    } \
} while (0)

#define ACCUM(S) do { \
    _Pragma("unroll") \
    for (int j_ = 0; j_ < 4; ++j_) { \
        float2 f0_ = unpack2(S##c0[j_]); \
        float2 f1_ = unpack2(S##c1[j_]); \
        float2 f2_ = unpack2(S##c2[j_]); \
        float spc_ = __half2float(S##sp[j_]); \
        S0  += f0_.x * spc_; \
        T10 += (f1_.x * S##d0[j_]) * spc_; \
        T11 += (f1_.x * S##d1[j_]) * spc_; \
        T12 += (f1_.x * S##d2[j_]) * spc_; \
        if (lo) { \
            float2 v01_ = __half22float2(S##v01[j_]); \
            float v2_ = __half2float(S##v2[j_]); \
            float pdot_ = S##d0[j_] * v01_.x + S##d1[j_] * v01_.y + S##d2[j_] * v2_; \
            A1 += f0_.y * pdot_; \
            float qp_ = f2_.x * pdot_; \
            V0 += f1_.y * v01_.x + qp_ * S##d0[j_]; \
            V1 += f1_.y * v01_.y + qp_ * S##d1[j_]; \
            V2 += f1_.y * v2_ + qp_ * S##d2[j_]; \
        } \
    } \
} while (0)

    int i = beg;
    LOADG(A, i);
    i += 4;
    int pend = 0;
    while (i < end) {
        if (pend == 0) { LOADG(B, i); ACCUM(A); pend = 1; }
        else           { LOADG(A, i); ACCUM(B); pend = 0; }
        i += 4;
    }
    if (pend == 0) ACCUM(A); else ACCUM(B);

#undef LOADG
#undef ACCUM
#undef DECLSET

    // agg_s[c] = S0 + sum_h A1[h] * Uvs[h,c]
    float aggs = S0;
    for (int h2 = 0; h2 < 32; ++h2)
        aggs += __shfl(A1, h2) * sUvs[h2 * 64 + lane];
    as_out[(size_t)n * 64 + lane] = aggs;
    // agg_v[h,d] = V[h,d] + sum_c T1[c,d] * Usv[c,h]
    float av0 = V0, av1 = V1, av2 = V2;
    for (int c = 0; c < 64; ++c) {
        float uu = sUsv[c * 32 + h];
        av0 += __shfl(T10, c) * uu;
        av1 += __shfl(T11, c) * uu;
        av2 += __shfl(T12, c) * uu;
    }
    if (lo) {
        avT_out[(size_t)n * 32 + h] = av0;
        avT_out[(size_t)N * 32 + (size_t)n * 32 + h] = av1;
        avT_out[(size_t)2 * N * 32 + (size_t)n * 32 + h] = av2;
    }
}

// ---------------- host ----------------

extern "C" void kernel_launch(void* const* d_in, const int* in_sizes, int n_in,
                              void* d_out, int out_size, void* d_ws, size_t ws_size,
                              hipStream_t stream) {
    const float* pos    = (const float*)d_in[0];
    const float* sfeat  = (const float*)d_in[1];
    const float* vfeat  = (const float*)d_in[2];
    const float* shifts = (const float*)d_in[3];
    const int*   ei     = (const int*)d_in[4];
    const float* Ws     = (const float*)d_in[5];
    const float* Wv     = (const float*)d_in[6];
    const float* Uvs    = (const float*)d_in[7];
    const float* Usv    = (const float*)d_in[8];
    const float* Wr     = (const float*)d_in[9];
    const float* Wrb    = (const float*)d_in[10];
    const float* Wos    = (const float*)d_in[11];
    const float* Wov    = (const float*)d_in[12];
    float* out = (float*)d_out;

    const int N = in_sizes[0] / 3;
    const int E = in_sizes[4] / 2;
    const int Epad = E + 4;

    char* w = (char*)d_ws;
    auto alloc = [&](size_t bytes) {
        char* p = w;
        w += (bytes + 255) & ~(size_t)255;
        return p;
    };
    int* counts     = (int*)alloc((size_t)N * 4);
    int* row_ptr    = (int*)alloc((size_t)(N + 1) * 4);
    int* cursor     = (int*)alloc((size_t)N * 4);
    float* Ms12     = (float*)alloc(2 * 4096 * 4);
    float* Mv12     = (float*)alloc(2 * 1024 * 4);
    __half* feat    = (__half*)alloc((size_t)N * FSTR * 2);
    float* asB      = (float*)alloc((size_t)N * 64 * 4);
    float* avB      = (float*)alloc((size_t)N * 32 * 3 * 4);
    uint4* recG     = (uint4*)alloc((size_t)Epad * 16);
    uint4* recC     = (uint4*)alloc((size_t)3 * Epad * 16);

    hipMemsetAsync(counts, 0, (size_t)N * 4, stream);

    int eb = (E + 255) / 256;
    count_kernel<<<eb, 256, 0, stream>>>(ei, counts, E);
    scan_kernel<<<1, 1024, 0, stream>>>(counts, row_ptr, cursor, N);
    build_kernel<<<eb, 256, 0, stream>>>(ei, pos, shifts, Wr, Wrb, cursor, recG, recC, E, Epad);
    compose_kernel<<<40, 256, 0, stream>>>(Ws, Wv, Wos, Wov, Ms12, Mv12);

    int nb = (N + 3) / 4;

    // layer 0
    node_transform<0><<<nb, 256, 0, stream>>>(sfeat, vfeat, Ws, Wv, feat, nullptr, N);
    edge_agg<<<nb, 256, 0, stream>>>(recG, recC, row_ptr, feat, Uvs, Usv, asB, avB, N);
    // layer 1
    node_transform<1><<<nb, 256, 0, stream>>>(asB, avB, Ms12, Mv12, feat, nullptr, N);
    edge_agg<<<nb, 256, 0, stream>>>(recG, recC + (size_t)Epad, row_ptr, feat,
                                     Uvs + 2048, Usv + 2048, asB, avB, N);
    // layer 2
    node_transform<1><<<nb, 256, 0, stream>>>(asB, avB, Ms12 + 4096, Mv12 + 1024, feat, nullptr, N);
    edge_agg<<<nb, 256, 0, stream>>>(recG, recC + (size_t)2 * Epad, row_ptr, feat,
                                     Uvs + 4096, Usv + 4096, asB, avB, N);
    // final output transform
    node_transform<2><<<nb, 256, 0, stream>>>(asB, avB, Wos + 2 * 4096, Wov + 2 * 1024, nullptr, out, N);
}